// Round 1
// baseline (24880.301 us; speedup 1.0000x reference)
//
#include <hip/hip_runtime.h>
#include <stdint.h>

// ---------------------------------------------------------------------------
// GRU with pack_padded_sequence semantics on MI355X.
// Phase 1: pack weights to f16 (+ transposed/packed layouts, fused biases)
// Phase 2: MFMA f16 GEMM for hoisted input projections P = X @ Wc^T + bias
//          (tiles with t >= len[b] skipped entirely)
// Phase 3: persistent recurrence, one 1024-thread block per batch row,
//          v_dot2_f32_f16 dot products, weights streamed from L2.
// ---------------------------------------------------------------------------

typedef _Float16 h2_t __attribute__((ext_vector_type(2)));
typedef _Float16 h8_t __attribute__((ext_vector_type(8)));
typedef float    f4_t __attribute__((ext_vector_type(4)));
typedef unsigned int uint;

#define NB   64
#define NT   2048
#define ND   512
#define NH   512
#define NROW (NB * NT)          // 131072
#define NCOL 1536               // 2H + H

// workspace layout (bytes), all 16B aligned
static const size_t OFF_P  = 0;                          // f16 [131072][1536]
static const size_t OFF_WC = (size_t)NROW * NCOL * 2;    // f16 [1536][512]
static const size_t OFF_W1 = OFF_WC + 1536 * 512 * 2;    // f16 [64][1024][8]
static const size_t OFF_W2 = OFF_W1 + 1024 * 512 * 2;    // f16 [64][512][8]
static const size_t OFF_CB = OFF_W2 + 512 * 512 * 2;     // f32 [1536]

// ---------------------------------------------------------------------------
__device__ __forceinline__ float fdot2u(uint w, uint h, float c) {
#if __has_builtin(__builtin_amdgcn_fdot2)
    union U { uint u; h2_t h; };
    U a; a.u = w; U b; b.u = h;
    return __builtin_amdgcn_fdot2(a.h, b.h, c, false);
#else
    union U { uint u; h2_t h; };
    U a; a.u = w; U b; b.u = h;
    return c + (float)a.h[0] * (float)b.h[0] + (float)a.h[1] * (float)b.h[1];
#endif
}

// ---------------------------------------------------------------------------
// Phase 1: weight/bias packing
//   Wc  [1536][512] f16 : rows 0..1023 = W_i2h, rows 1024..1535 = W_i2o
//   W1T f16 flat [(k4*1024 + j)*8 + e] = W_h2h[j][k4*8+e]   (k-packed for dot2)
//   W2T f16 flat [(k4*512  + j)*8 + e] = W_h2o[j][k4*8+e]
//   cbias[n] = b_i2h[n]+b_h2h[n] (n<1024) else b_i2o[n-1024]+b_h2o[n-1024]
// ---------------------------------------------------------------------------
__global__ void pack_kernel(const float* __restrict__ Wi2h, const float* __restrict__ bi2h,
                            const float* __restrict__ Wh2h, const float* __restrict__ bh2h,
                            const float* __restrict__ Wi2o, const float* __restrict__ bi2o,
                            const float* __restrict__ Wh2o, const float* __restrict__ bh2o,
                            _Float16* __restrict__ Wc, _Float16* __restrict__ W1T,
                            _Float16* __restrict__ W2T, float* __restrict__ cbias)
{
    int id = blockIdx.x * 256 + threadIdx.x;
    if (id < 786432) {
        int n = id >> 9, k = id & 511;
        float v = (n < 1024) ? Wi2h[n * 512 + k] : Wi2o[(n - 1024) * 512 + k];
        Wc[id] = (_Float16)v;
    } else if (id < 786432 + 524288) {
        int lid = id - 786432;
        int k4 = lid >> 13, j = (lid >> 3) & 1023, e = lid & 7;
        W1T[lid] = (_Float16)Wh2h[j * 512 + (k4 << 3) + e];
    } else if (id < 786432 + 524288 + 262144) {
        int lid = id - (786432 + 524288);
        int k4 = lid >> 12, j = (lid >> 3) & 511, e = lid & 7;
        W2T[lid] = (_Float16)Wh2o[j * 512 + (k4 << 3) + e];
    } else if (id < 786432 + 524288 + 262144 + 1536) {
        int n = id - (786432 + 524288 + 262144);
        cbias[n] = (n < 1024) ? (bi2h[n] + bh2h[n]) : (bi2o[n - 1024] + bh2o[n - 1024]);
    }
}

// ---------------------------------------------------------------------------
// Phase 2: P[row][n] = sum_k X[row][k] * Wc[n][k] + cbias[n], f16 out.
// 128x128 tile per 256-thread block, 16x16x32 f16 MFMA, fp32 X converted to
// f16 during LDS staging. Block->tile mapping keeps one row-tile's X within
// one XCD's L2 across its 12 N-tiles (bid%8 ~ XCD heuristic).
// ---------------------------------------------------------------------------
__global__ void gemm_proj(const float* __restrict__ X, const _Float16* __restrict__ Wc,
                          const float* __restrict__ cbias, const int* __restrict__ lens,
                          _Float16* __restrict__ P)
{
    int bid  = blockIdx.x;
    int xcd  = bid & 7;
    int slot = bid >> 3;
    int nt   = slot % 12;          // N-tile (fastest within an XCD's slot stream)
    int tyl  = slot / 12;          // 0..127
    int ty   = xcd * 128 + tyl;    // row-tile 0..1023

    int b  = ty >> 4;              // (ty*128)/2048
    int t0 = (ty << 7) & 2047;
    if (t0 >= lens[b]) return;     // projections never read -> skip

    int rowbase = ty << 7;
    int nbase   = nt << 7;

    __shared__ _Float16 As[128][40];   // +8 pad, 80B row stride (16B aligned)
    __shared__ _Float16 Bs[128][40];

    int tid  = threadIdx.x;
    int lane = tid & 63, w = tid >> 6;
    int wm = w >> 1, wn = w & 1;
    int fr = lane & 15, quad = lane >> 4;

    f4_t acc[4][4] = {};

    int sr = tid >> 2;             // 0..63
    int sc = (tid & 3) << 3;       // 0,8,16,24

    for (int kc = 0; kc < 16; ++kc) {
        int k0 = kc << 5;
        // stage A (fp32 -> f16) and B (f16)
#pragma unroll
        for (int p = 0; p < 2; ++p) {
            int r = sr + p * 64;
            const float* asrc = X + (size_t)(rowbase + r) * 512 + k0 + sc;
            f4_t a0 = *(const f4_t*)asrc;
            f4_t a1 = *(const f4_t*)(asrc + 4);
            h8_t hv;
            hv[0] = (_Float16)a0[0]; hv[1] = (_Float16)a0[1];
            hv[2] = (_Float16)a0[2]; hv[3] = (_Float16)a0[3];
            hv[4] = (_Float16)a1[0]; hv[5] = (_Float16)a1[1];
            hv[6] = (_Float16)a1[2]; hv[7] = (_Float16)a1[3];
            *(h8_t*)&As[r][sc] = hv;
            *(h8_t*)&Bs[r][sc] = *(const h8_t*)(Wc + (size_t)(nbase + r) * 512 + k0 + sc);
        }
        __syncthreads();

        h8_t af[4], bf[4];
#pragma unroll
        for (int i = 0; i < 4; ++i) {
            af[i] = *(const h8_t*)&As[wm * 64 + i * 16 + fr][quad * 8];
            bf[i] = *(const h8_t*)&Bs[wn * 64 + i * 16 + fr][quad * 8];
        }
#pragma unroll
        for (int mi = 0; mi < 4; ++mi)
#pragma unroll
            for (int ni = 0; ni < 4; ++ni)
                acc[mi][ni] = __builtin_amdgcn_mfma_f32_16x16x32_f16(
                    af[mi], bf[ni], acc[mi][ni], 0, 0, 0);
        __syncthreads();
    }

    // epilogue: D row = quad*4+reg, col = fr  (verified gfx950 C/D layout)
#pragma unroll
    for (int ni = 0; ni < 4; ++ni) {
        int gcol = nbase + wn * 64 + ni * 16 + fr;
        float bias = cbias[gcol];
#pragma unroll
        for (int mi = 0; mi < 4; ++mi) {
            int grow0 = rowbase + wm * 64 + mi * 16 + quad * 4;
#pragma unroll
            for (int rg = 0; rg < 4; ++rg)
                P[(size_t)(grow0 + rg) * NCOL + gcol] = (_Float16)(acc[mi][ni][rg] + bias);
        }
    }
}

// ---------------------------------------------------------------------------
// Phase 3: recurrence. One block (1024 threads) per batch row.
// Round 1: thread j computes preact_j (j<512 -> z, j>=512 -> r) via 256 f16
//          dot2 pairs against h (packed f16 in LDS).
// Round 2: threads 0..511 compute s_j, then h_new and the masked output.
// Early exit at t == len[b]; zero-fill padded rows; write final_h.
// ---------------------------------------------------------------------------
__global__ __launch_bounds__(1024)
void gru_rec(const _Float16* __restrict__ P, const _Float16* __restrict__ W1T,
             const _Float16* __restrict__ W2T, const int* __restrict__ lens,
             float* __restrict__ out)
{
    __shared__ uint4 hp4[64];      // h packed as 512 f16
    __shared__ uint4 gp4[64];      // g packed as 512 f16
    __shared__ float hf[512];      // h in fp32

    int b   = blockIdx.x;
    int tid = threadIdx.x;
    int len = lens[b];

    if (tid < 512) hf[tid] = 0.f;
    if (tid < 64)  hp4[tid] = make_uint4(0, 0, 0, 0);
    __syncthreads();

    const uint4* w1 = (const uint4*)W1T;   // [64][1024] uint4 (8 f16 each)
    const uint4* w2 = (const uint4*)W2T;   // [64][512]  uint4

    for (int t = 0; t < len; ++t) {
        const _Float16* prow = P + (size_t)(b * NT + t) * NCOL;

        // ---- round 1: y_j = P_zr[j] + h . W_h2h[j,:]
        float ya = (float)prow[tid], yb = 0.f;
#pragma unroll 4
        for (int k4 = 0; k4 < 64; ++k4) {
            uint4 wv = w1[(k4 << 10) + tid];
            uint4 hv = hp4[k4];
            ya = fdot2u(wv.x, hv.x, ya);
            yb = fdot2u(wv.y, hv.y, yb);
            ya = fdot2u(wv.z, hv.z, ya);
            yb = fdot2u(wv.w, hv.w, yb);
        }
        float y = ya + yb;

        float zval = y, hj = 0.f;
        if (tid < 512) {
            hj = hf[tid];
        } else {
            float sr = 1.f / (1.f + __expf(-y));
            float g  = hf[tid - 512] * sr;
            ((_Float16*)gp4)[tid - 512] = (_Float16)g;
        }
        __syncthreads();

        // ---- round 2: s_j = P_o[j] + g . W_h2o[j,:]; update h
        if (tid < 512) {
            float sa = (float)prow[1024 + tid], sb = 0.f;
#pragma unroll 4
            for (int k4 = 0; k4 < 64; ++k4) {
                uint4 wv = w2[(k4 << 9) + tid];
                uint4 gv = gp4[k4];
                sa = fdot2u(wv.x, gv.x, sa);
                sb = fdot2u(wv.y, gv.y, sb);
                sa = fdot2u(wv.z, gv.z, sa);
                sb = fdot2u(wv.w, gv.w, sb);
            }
            float s  = sa + sb;
            float zs = 1.f / (1.f + __expf(-zval));
            float th = 1.f - 2.f / (__expf(2.f * s) + 1.f);
            float hn = (1.f - zs) * hj + zs * th;
            out[(size_t)(b * NT + t) * NH + tid] = hn;
            hf[tid] = hn;
            ((_Float16*)hp4)[tid] = (_Float16)hn;
        }
        __syncthreads();
    }

    // zero-fill padded rows  (out = 0 where t >= len)
    size_t zelems = (size_t)(NT - len) * NH;
    f4_t* z4 = (f4_t*)(out + (size_t)(b * NT + len) * NH);
    f4_t zero = {0.f, 0.f, 0.f, 0.f};
    for (size_t i = tid; i < (zelems >> 2); i += 1024) z4[i] = zero;

    // final hidden state (frozen at t = len)
    if (tid < 512) out[(size_t)NB * NT * NH + b * NH + tid] = hf[tid];
}

// ---------------------------------------------------------------------------
extern "C" void kernel_launch(void* const* d_in, const int* in_sizes, int n_in,
                              void* d_out, int out_size, void* d_ws, size_t ws_size,
                              hipStream_t stream)
{
    const float* X    = (const float*)d_in[0];
    const int*  lens  = (const int*)d_in[1];
    const float* Wi2h = (const float*)d_in[2];
    const float* bi2h = (const float*)d_in[3];
    const float* Wh2h = (const float*)d_in[4];
    const float* bh2h = (const float*)d_in[5];
    const float* Wi2o = (const float*)d_in[6];
    const float* bi2o = (const float*)d_in[7];
    const float* Wh2o = (const float*)d_in[8];
    const float* bh2o = (const float*)d_in[9];

    char* ws = (char*)d_ws;
    _Float16* P   = (_Float16*)(ws + OFF_P);
    _Float16* Wc  = (_Float16*)(ws + OFF_WC);
    _Float16* W1T = (_Float16*)(ws + OFF_W1);
    _Float16* W2T = (_Float16*)(ws + OFF_W2);
    float*    cb  = (float*)(ws + OFF_CB);
    float*    out = (float*)d_out;

    pack_kernel<<<6151, 256, 0, stream>>>(Wi2h, bi2h, Wh2h, bh2h,
                                          Wi2o, bi2o, Wh2o, bh2o,
                                          Wc, W1T, W2T, cb);
    gemm_proj<<<12288, 256, 0, stream>>>(X, Wc, cb, lens, P);
    gru_rec<<<NB, 1024, 0, stream>>>(P, W1T, W2T, lens, out);
}